// Round 1
// baseline (475.455 us; speedup 1.0000x reference)
//
#include <hip/hip_runtime.h>
#include <math.h>

#define NJ 140
#define NV 13059
#define NB 512
#define NBONES 28

#define JC 20          // joints per LDS chunk (140 = 7*20)
#define BT 32          // batches per block
#define VT 64          // vertices per block
#define SROW 244       // sG row stride in floats (20*12 + 4 pad), 976B: 16B-aligned

// ---------------- Kernel A: forward kinematics via pointer jumping ----------
// One block per batch. Joints j<140 build local matrices L_j (3x4, bottom row
// implicit [0,0,0,1]); 8 rounds of pointer jumping compose G_j = prod(root..j).
// Emits G_rel (b,j,12) fp32 to ws and J_out to d_out tail.
__global__ __launch_bounds__(192) void kin_kernel(
    const float* __restrict__ pose,         // (NB, NJ*3)
    const float* __restrict__ bone_lengths, // (NB, NBONES)
    const float* __restrict__ cbl,          // (NB)
    const float* __restrict__ trans,        // (NB, 3)
    const float* __restrict__ scale,        // (NB)
    const float* __restrict__ t_pose,       // (NJ, 3)
    const int*   __restrict__ parent,       // (NJ)
    const int*   __restrict__ bone_mapper,  // (NJ)
    float* __restrict__ grel,               // ws: (NB, NJ, 12)
    float* __restrict__ jout)               // (NB, NJ, 3)
{
    __shared__ float M0[NJ][12];
    __shared__ float M1[NJ][12];
    __shared__ int   a0[NJ];
    __shared__ int   a1[NJ];

    const int b = blockIdx.x;
    const int t = threadIdx.x;

    if (t < NJ) {
        const int j = t;
        float z = pose[b*(NJ*3) + 3*j + 0];
        float y = pose[b*(NJ*3) + 3*j + 1];
        float x = pose[b*(NJ*3) + 3*j + 2];
        float cx = cosf(x), sx = sinf(x);
        float cy = cosf(y), sy = sinf(y);
        float cz = cosf(z), sz = sinf(z);
        float r00 = cz*cy;
        float r01 = cz*sy*sx - sz*cx;
        float r02 = cz*sy*cx + sz*sx;
        float r10 = sz*cy;
        float r11 = sz*sy*sx + cz*cx;
        float r12 = sz*sy*cx - cz*sx;
        float r20 = -sy;
        float r21 = cy*sx;
        float r22 = cy*cx;
        float t0, t1, t2;
        int p = parent[j];
        if (j == 0) {
            t0 = t_pose[0]; t1 = t_pose[1]; t2 = t_pose[2];
        } else {
            float ox = t_pose[3*j+0] - t_pose[3*p+0];
            float oy = t_pose[3*j+1] - t_pose[3*p+1];
            float oz = t_pose[3*j+2] - t_pose[3*p+2];
            float s;
            if (j == 1) {
                s = cbl[b];                       // scale_per[:,0] override
            } else {
                int blid = bone_mapper[j];        // blid = bone_mapper[1:][j-1]
                if (blid >= 0) {
                    float bv = bone_lengths[b*NBONES + blid];
                    s = 2.0f / (1.0f + expf(-bv*0.2f));   // 2*sigmoid(x/5)
                } else {
                    s = 1.0f;
                }
            }
            t0 = ox*s; t1 = oy*s; t2 = oz*s;
        }
        M0[j][0]=r00; M0[j][1]=r01; M0[j][2]=r02;  M0[j][3]=t0;
        M0[j][4]=r10; M0[j][5]=r11; M0[j][6]=r12;  M0[j][7]=t1;
        M0[j][8]=r20; M0[j][9]=r21; M0[j][10]=r22; M0[j][11]=t2;
        a0[j] = (j == 0) ? -1 : p;
    }
    __syncthreads();

    // 8 rounds: after round r, pointer spans 2^(r+1) ancestors; depth <= 139 < 256.
    float* src = &M0[0][0]; float* dst = &M1[0][0];
    int* as = a0; int* ad = a1;
    for (int r = 0; r < 8; ++r) {
        if (t < NJ) {
            int a = as[t];
            const float* Mi = src + t*12;
            float* Do = dst + t*12;
            if (a >= 0) {
                const float* Mp = src + a*12;
                #pragma unroll
                for (int m = 0; m < 3; ++m) {
                    float p0 = Mp[m*4+0], p1 = Mp[m*4+1], p2 = Mp[m*4+2], p3 = Mp[m*4+3];
                    Do[m*4+0] = p0*Mi[0] + p1*Mi[4] + p2*Mi[8];
                    Do[m*4+1] = p0*Mi[1] + p1*Mi[5] + p2*Mi[9];
                    Do[m*4+2] = p0*Mi[2] + p1*Mi[6] + p2*Mi[10];
                    Do[m*4+3] = p0*Mi[3] + p1*Mi[7] + p2*Mi[11] + p3;
                }
                ad[t] = as[a];
            } else {
                #pragma unroll
                for (int e = 0; e < 12; ++e) Do[e] = Mi[e];
                ad[t] = -1;
            }
        }
        __syncthreads();
        float* tf = src; src = dst; dst = tf;
        int* ti = as; as = ad; ad = ti;
    }

    if (t < NJ) {
        const int j = t;
        const float* G = src + j*12;
        float sb = scale[b];
        float tr0 = trans[b*3+0], tr1 = trans[b*3+1], tr2 = trans[b*3+2];
        float* jo = jout + ((size_t)b*NJ + j)*3;
        jo[0] = G[3]*sb  + tr0;
        jo[1] = G[7]*sb  + tr1;
        jo[2] = G[11]*sb + tr2;
        float jx = t_pose[3*j+0], jy = t_pose[3*j+1], jz = t_pose[3*j+2];
        float* o = grel + ((size_t)b*NJ + j)*12;
        o[0]=G[0]; o[1]=G[1]; o[2]=G[2];   o[3] = G[3]  - (G[0]*jx + G[1]*jy + G[2]*jz);
        o[4]=G[4]; o[5]=G[5]; o[6]=G[6];   o[7] = G[7]  - (G[4]*jx + G[5]*jy + G[6]*jz);
        o[8]=G[8]; o[9]=G[9]; o[10]=G[10]; o[11]= G[11] - (G[8]*jx + G[9]*jy + G[10]*jz);
    }
}

// ---------------- Kernel B: blend skinning (fp32, register-tiled) ----------
// Block: 64 vertices x 32 batches; thread: 4 vertices x 2 batches.
// V[b,v,m] = sum_j [ (w*x)G[m,0] + (w*y)G[m,1] + (w*z)G[m,2] + w*G[m,3] ]
// Thread map: bt = t>>4 (4 per wave -> G rows broadcast, 4 disjoint bank
// groups at stride 2*SROW=488 floats), vt = t&15 (contiguous w b128 reads).
__global__ __launch_bounds__(256) void skin_kernel(
    const float* __restrict__ grel,        // (NB, NJ, 12)
    const float* __restrict__ weights,     // (NV, NJ)
    const float* __restrict__ v_template,  // (NV, 3)
    const float* __restrict__ scale,       // (NB)
    const float* __restrict__ trans,       // (NB, 3)
    float* __restrict__ vout)              // (NB, NV, 3)
{
    __shared__ float sG[BT][SROW];   // per-batch G chunk: JC*12 floats + pad
    __shared__ float sW[JC][VT];     // weights chunk, [j][v] for b128 reads

    const int t = threadIdx.x;
    const int bt = t >> 4;           // 0..15
    const int vt = t & 15;           // 0..15
    const int v_base = blockIdx.x * VT;
    const int b_base = blockIdx.y * BT;

    float X[4], Y[4], Z[4];
    #pragma unroll
    for (int i = 0; i < 4; ++i) {
        int v = v_base + vt*4 + i;
        if (v > NV-1) v = NV-1;
        X[i] = v_template[v*3+0];
        Y[i] = v_template[v*3+1];
        Z[i] = v_template[v*3+2];
    }

    float acc[2][4][3];
    #pragma unroll
    for (int bb = 0; bb < 2; ++bb)
        #pragma unroll
        for (int i = 0; i < 4; ++i) {
            acc[bb][i][0] = 0.f; acc[bb][i][1] = 0.f; acc[bb][i][2] = 0.f;
        }

    const float4* g4 = (const float4*)grel;   // row = NJ*12/4 = 420 float4

    for (int c = 0; c < 7; ++c) {
        const int j0 = c * JC;
        __syncthreads();
        // stage G: BT batches x 60 float4 (coalesced 240-float runs)
        for (int i = t; i < BT*60; i += 256) {
            int bl = i / 60;
            int e  = i - bl*60;
            float4 g = g4[(size_t)(b_base + bl)*420 + j0*3 + e];
            *(float4*)&sG[bl][e*4] = g;
        }
        // stage W: JC x VT  (transposed: [j][v])
        for (int i = t; i < JC*VT; i += 256) {
            int vl = i / JC;
            int jl = i - vl*JC;
            int v = v_base + vl; if (v > NV-1) v = NV-1;
            sW[jl][vl] = weights[(size_t)v*NJ + j0 + jl];
        }
        __syncthreads();

        #pragma unroll 5
        for (int jl = 0; jl < JC; ++jl) {
            float4 w = *(const float4*)&sW[jl][vt*4];
            float W4[4] = {w.x, w.y, w.z, w.w};
            float PX[4], PY[4], PZ[4];
            #pragma unroll
            for (int i = 0; i < 4; ++i) {
                PX[i] = W4[i]*X[i]; PY[i] = W4[i]*Y[i]; PZ[i] = W4[i]*Z[i];
            }
            #pragma unroll
            for (int bb = 0; bb < 2; ++bb) {
                const float* Gp = &sG[bt*2 + bb][jl*12];
                float4 g0 = *(const float4*)(Gp + 0);
                float4 g1 = *(const float4*)(Gp + 4);
                float4 g2 = *(const float4*)(Gp + 8);
                #pragma unroll
                for (int i = 0; i < 4; ++i) {
                    acc[bb][i][0] += PX[i]*g0.x + PY[i]*g0.y + PZ[i]*g0.z + W4[i]*g0.w;
                    acc[bb][i][1] += PX[i]*g1.x + PY[i]*g1.y + PZ[i]*g1.z + W4[i]*g1.w;
                    acc[bb][i][2] += PX[i]*g2.x + PY[i]*g2.y + PZ[i]*g2.z + W4[i]*g2.w;
                }
            }
        }
    }

    #pragma unroll
    for (int bb = 0; bb < 2; ++bb) {
        int b = b_base + bt*2 + bb;
        float sb = scale[b];
        float t0 = trans[b*3+0], t1 = trans[b*3+1], t2 = trans[b*3+2];
        #pragma unroll
        for (int i = 0; i < 4; ++i) {
            int v = v_base + vt*4 + i;
            if (v < NV) {
                size_t o = ((size_t)b*NV + v)*3;
                vout[o+0] = acc[bb][i][0]*sb + t0;
                vout[o+1] = acc[bb][i][1]*sb + t1;
                vout[o+2] = acc[bb][i][2]*sb + t2;
            }
        }
    }
}

extern "C" void kernel_launch(void* const* d_in, const int* in_sizes, int n_in,
                              void* d_out, int out_size, void* d_ws, size_t ws_size,
                              hipStream_t stream) {
    const float* pose         = (const float*)d_in[0];
    const float* bone_lengths = (const float*)d_in[1];
    const float* cbl          = (const float*)d_in[2];
    const float* trans        = (const float*)d_in[3];
    const float* scale        = (const float*)d_in[4];
    const float* v_template   = (const float*)d_in[5];
    const float* t_pose       = (const float*)d_in[6];
    const float* weights      = (const float*)d_in[7];
    const int*   parent       = (const int*)d_in[8];
    const int*   bone_mapper  = (const int*)d_in[9];

    float* vout = (float*)d_out;                       // (NB,NV,3) first
    float* jout = vout + (size_t)NB*NV*3;              // then (NB,NJ,3)
    float* grel = (float*)d_ws;                        // 512*140*12*4 = 3.3 MB

    kin_kernel<<<NB, 192, 0, stream>>>(pose, bone_lengths, cbl, trans, scale,
                                       t_pose, parent, bone_mapper, grel, jout);

    dim3 grid((NV + VT - 1)/VT, NB/BT);                // 205 x 16
    skin_kernel<<<grid, 256, 0, stream>>>(grel, weights, v_template, scale,
                                          trans, vout);
}

// Round 2
// 343.957 us; speedup vs baseline: 1.3823x; 1.3823x over previous
//
#include <hip/hip_runtime.h>
#include <math.h>

#define NJ 140
#define NV 13059
#define NVP 13312      // NV padded to 52*256 (16B-aligned rows, zero tail)
#define NB 512
#define NBONES 28

// ---------------- Kernel 0: transpose weights (NV,NJ) -> wT (NJ,NVP) -------
__global__ __launch_bounds__(256) void transpose_w(
    const float* __restrict__ weights,   // (NV, NJ)
    float* __restrict__ wT)              // (NJ, NVP), zero-padded v >= NV
{
    __shared__ float tile[64][141];      // +1 pad breaks bank alignment
    const int vbase = blockIdx.x * 64;
    const int t = threadIdx.x;
    for (int i = t; i < 64*NJ; i += 256) {
        int vl = i / NJ;
        int jl = i - vl*NJ;
        int v = vbase + vl;
        tile[vl][jl] = (v < NV) ? weights[(size_t)v*NJ + jl] : 0.0f;
    }
    __syncthreads();
    for (int i = t; i < NJ*64; i += 256) {
        int jl = i >> 6;
        int vl = i & 63;
        wT[(size_t)jl*NVP + vbase + vl] = tile[vl][jl];
    }
}

// ---------------- Kernel A: forward kinematics via pointer jumping ----------
__global__ __launch_bounds__(192) void kin_kernel(
    const float* __restrict__ pose,         // (NB, NJ*3)
    const float* __restrict__ bone_lengths, // (NB, NBONES)
    const float* __restrict__ cbl,          // (NB)
    const float* __restrict__ trans,        // (NB, 3)
    const float* __restrict__ scale,        // (NB)
    const float* __restrict__ t_pose,       // (NJ, 3)
    const int*   __restrict__ parent,       // (NJ)
    const int*   __restrict__ bone_mapper,  // (NJ)
    float* __restrict__ grel,               // ws: (NB, NJ, 12)
    float* __restrict__ jout)               // (NB, NJ, 3)
{
    __shared__ float M0[NJ][12];
    __shared__ float M1[NJ][12];
    __shared__ int   a0[NJ];
    __shared__ int   a1[NJ];

    const int b = blockIdx.x;
    const int t = threadIdx.x;

    if (t < NJ) {
        const int j = t;
        float z = pose[b*(NJ*3) + 3*j + 0];
        float y = pose[b*(NJ*3) + 3*j + 1];
        float x = pose[b*(NJ*3) + 3*j + 2];
        float cx = cosf(x), sx = sinf(x);
        float cy = cosf(y), sy = sinf(y);
        float cz = cosf(z), sz = sinf(z);
        float r00 = cz*cy;
        float r01 = cz*sy*sx - sz*cx;
        float r02 = cz*sy*cx + sz*sx;
        float r10 = sz*cy;
        float r11 = sz*sy*sx + cz*cx;
        float r12 = sz*sy*cx - cz*sx;
        float r20 = -sy;
        float r21 = cy*sx;
        float r22 = cy*cx;
        float t0, t1, t2;
        int p = parent[j];
        if (j == 0) {
            t0 = t_pose[0]; t1 = t_pose[1]; t2 = t_pose[2];
        } else {
            float ox = t_pose[3*j+0] - t_pose[3*p+0];
            float oy = t_pose[3*j+1] - t_pose[3*p+1];
            float oz = t_pose[3*j+2] - t_pose[3*p+2];
            float s;
            if (j == 1) {
                s = cbl[b];
            } else {
                int blid = bone_mapper[j];
                if (blid >= 0) {
                    float bv = bone_lengths[b*NBONES + blid];
                    s = 2.0f / (1.0f + expf(-bv*0.2f));   // 2*sigmoid(x/5)
                } else {
                    s = 1.0f;
                }
            }
            t0 = ox*s; t1 = oy*s; t2 = oz*s;
        }
        M0[j][0]=r00; M0[j][1]=r01; M0[j][2]=r02;  M0[j][3]=t0;
        M0[j][4]=r10; M0[j][5]=r11; M0[j][6]=r12;  M0[j][7]=t1;
        M0[j][8]=r20; M0[j][9]=r21; M0[j][10]=r22; M0[j][11]=t2;
        a0[j] = (j == 0) ? -1 : p;
    }
    __syncthreads();

    float* src = &M0[0][0]; float* dst = &M1[0][0];
    int* as = a0; int* ad = a1;
    for (int r = 0; r < 8; ++r) {
        if (t < NJ) {
            int a = as[t];
            const float* Mi = src + t*12;
            float* Do = dst + t*12;
            if (a >= 0) {
                const float* Mp = src + a*12;
                #pragma unroll
                for (int m = 0; m < 3; ++m) {
                    float p0 = Mp[m*4+0], p1 = Mp[m*4+1], p2 = Mp[m*4+2], p3 = Mp[m*4+3];
                    Do[m*4+0] = p0*Mi[0] + p1*Mi[4] + p2*Mi[8];
                    Do[m*4+1] = p0*Mi[1] + p1*Mi[5] + p2*Mi[9];
                    Do[m*4+2] = p0*Mi[2] + p1*Mi[6] + p2*Mi[10];
                    Do[m*4+3] = p0*Mi[3] + p1*Mi[7] + p2*Mi[11] + p3;
                }
                ad[t] = as[a];
            } else {
                #pragma unroll
                for (int e = 0; e < 12; ++e) Do[e] = Mi[e];
                ad[t] = -1;
            }
        }
        __syncthreads();
        float* tf = src; src = dst; dst = tf;
        int* ti = as; as = ad; ad = ti;
    }

    if (t < NJ) {
        const int j = t;
        const float* G = src + j*12;
        float sb = scale[b];
        float tr0 = trans[b*3+0], tr1 = trans[b*3+1], tr2 = trans[b*3+2];
        float* jo = jout + ((size_t)b*NJ + j)*3;
        jo[0] = G[3]*sb  + tr0;
        jo[1] = G[7]*sb  + tr1;
        jo[2] = G[11]*sb + tr2;
        float jx = t_pose[3*j+0], jy = t_pose[3*j+1], jz = t_pose[3*j+2];
        float* o = grel + ((size_t)b*NJ + j)*12;
        o[0]=G[0]; o[1]=G[1]; o[2]=G[2];   o[3] = G[3]  - (G[0]*jx + G[1]*jy + G[2]*jz);
        o[4]=G[4]; o[5]=G[5]; o[6]=G[6];   o[7] = G[7]  - (G[4]*jx + G[5]*jy + G[6]*jz);
        o[8]=G[8]; o[9]=G[9]; o[10]=G[10]; o[11]= G[11] - (G[8]*jx + G[9]*jy + G[10]*jz);
    }
}

// ---------------- Kernel B: blend skinning — scalar-G, no LDS --------------
// Wave = 2 batches (uniform via readfirstlane -> G in SGPRs via s_load).
// Thread = 4 consecutive vertices x 2 batches; T accumulators 2*4*12 = 96 VGPR.
// Per j per wave: 1 global_load_dwordx4 (w, coalesced) + 6 s_load_dwordx4 (G)
// + 96 v_fmac_f32 (SGPR x VGPR). No LDS, no __syncthreads in the main loop.
__global__ __launch_bounds__(256) void skin_kernel(
    const float* __restrict__ wT,          // (NJ, NVP) transposed weights
    const float* __restrict__ grel,        // (NB, NJ, 12)
    const float* __restrict__ v_template,  // (NV, 3)
    const float* __restrict__ scale,       // (NB)
    const float* __restrict__ trans,       // (NB, 3)
    float* __restrict__ vout)              // (NB, NV, 3)
{
    const int t    = threadIdx.x;
    const int lane = t & 63;
    const int wave = t >> 6;
    const int v0   = blockIdx.x * 256 + lane * 4;     // 4 consecutive vertices
    const int b0   = __builtin_amdgcn_readfirstlane(blockIdx.y * 8 + wave * 2);
    const int b1   = b0 + 1;

    const float* ga_base = grel + (size_t)b0 * (NJ * 12);
    const float* gb_base = grel + (size_t)b1 * (NJ * 12);

    float T0[4][12];
    float T1[4][12];
    #pragma unroll
    for (int i = 0; i < 4; ++i)
        #pragma unroll
        for (int m = 0; m < 12; ++m) { T0[i][m] = 0.f; T1[i][m] = 0.f; }

    #pragma unroll 2
    for (int j = 0; j < NJ; ++j) {
        float4 w = *(const float4*)(wT + (size_t)j * NVP + v0);
        const float* ga = ga_base + j * 12;
        const float* gb = gb_base + j * 12;
        #pragma unroll
        for (int m = 0; m < 12; ++m) {
            float gA = ga[m];
            float gB = gb[m];
            T0[0][m] += w.x * gA;
            T0[1][m] += w.y * gA;
            T0[2][m] += w.z * gA;
            T0[3][m] += w.w * gA;
            T1[0][m] += w.x * gB;
            T1[1][m] += w.y * gB;
            T1[2][m] += w.z * gB;
            T1[3][m] += w.w * gB;
        }
    }

    // Epilogue: V = T * [x,y,z,1] * s + trans
    #pragma unroll
    for (int bb = 0; bb < 2; ++bb) {
        const int b = (bb == 0) ? b0 : b1;
        float sb = scale[b];
        float t0 = trans[b*3+0], t1 = trans[b*3+1], t2 = trans[b*3+2];
        #pragma unroll
        for (int i = 0; i < 4; ++i) {
            int v = v0 + i;
            if (v < NV) {
                float x = v_template[v*3+0];
                float y = v_template[v*3+1];
                float z = v_template[v*3+2];
                const float (*T)[12] = (bb == 0) ? T0 : T1;
                size_t o = ((size_t)b * NV + v) * 3;
                vout[o+0] = (T[i][0]*x + T[i][1]*y + T[i][2]*z  + T[i][3])  * sb + t0;
                vout[o+1] = (T[i][4]*x + T[i][5]*y + T[i][6]*z  + T[i][7])  * sb + t1;
                vout[o+2] = (T[i][8]*x + T[i][9]*y + T[i][10]*z + T[i][11]) * sb + t2;
            }
        }
    }
}

extern "C" void kernel_launch(void* const* d_in, const int* in_sizes, int n_in,
                              void* d_out, int out_size, void* d_ws, size_t ws_size,
                              hipStream_t stream) {
    const float* pose         = (const float*)d_in[0];
    const float* bone_lengths = (const float*)d_in[1];
    const float* cbl          = (const float*)d_in[2];
    const float* trans        = (const float*)d_in[3];
    const float* scale        = (const float*)d_in[4];
    const float* v_template   = (const float*)d_in[5];
    const float* t_pose       = (const float*)d_in[6];
    const float* weights      = (const float*)d_in[7];
    const int*   parent       = (const int*)d_in[8];
    const int*   bone_mapper  = (const int*)d_in[9];

    float* vout = (float*)d_out;                         // (NB,NV,3)
    float* jout = vout + (size_t)NB*NV*3;                // (NB,NJ,3)

    float* wT   = (float*)d_ws;                          // NJ*NVP*4 = 7.45 MB
    float* grel = wT + (size_t)NJ*NVP;                   // NB*NJ*12*4 = 3.44 MB

    transpose_w<<<NVP/64, 256, 0, stream>>>(weights, wT);

    kin_kernel<<<NB, 192, 0, stream>>>(pose, bone_lengths, cbl, trans, scale,
                                       t_pose, parent, bone_mapper, grel, jout);

    dim3 grid(NVP/256, NB/8);                            // 52 x 64
    skin_kernel<<<grid, 256, 0, stream>>>(wT, grel, v_template, scale,
                                          trans, vout);
}

// Round 3
// 206.792 us; speedup vs baseline: 2.2992x; 1.6633x over previous
//
#include <hip/hip_runtime.h>
#include <math.h>

#define NJ 140
#define NV 13059
#define NB 512
#define NBONES 28

#define MPAD 13184          // 103 * 128
#define KPAD 576            // 140*4 = 560, padded to 18*32
#define NN   1536           // 512 * 3
#define BM   128
#define BN   96
#define BK   32
#define KSTEPS (KPAD/BK)    // 18
#define LDK  56             // LDS row stride in f16 (112B: 16B-aligned, 2-way banks)

typedef _Float16 f16x8 __attribute__((ext_vector_type(8)));
typedef _Float16 f16x4 __attribute__((ext_vector_type(4)));
typedef float    f32x4 __attribute__((ext_vector_type(4)));

// ---------------- Kernel 1: fused prep(A) + kinematics(B_T, jout) ----------
// blocks [0,512): kinematics for batch b=blockIdx.x (pointer jumping),
//   emits B_T[n=b*3+c][k=j*4+k4] = G_rel[b,j,c,k4] (f16) + zero pad + jout.
// blocks [512, 512+PREPB): build A[v][k] = w[v,j]*vh[v,k4] (f16), zero-padded.
#define PREPB ((MPAD*KPAD/8)/256)   // 3708

__global__ __launch_bounds__(256) void prep_kin_kernel(
    const float* __restrict__ pose,         // (NB, NJ*3)
    const float* __restrict__ bone_lengths, // (NB, NBONES)
    const float* __restrict__ cbl,          // (NB)
    const float* __restrict__ trans,        // (NB, 3)
    const float* __restrict__ scale,        // (NB)
    const float* __restrict__ v_template,   // (NV, 3)
    const float* __restrict__ t_pose,       // (NJ, 3)
    const int*   __restrict__ parent,       // (NJ)
    const int*   __restrict__ bone_mapper,  // (NJ)
    const float* __restrict__ weights,      // (NV, NJ)
    _Float16* __restrict__ Aout,            // (MPAD, KPAD)
    _Float16* __restrict__ Bt,              // (NN, KPAD)
    float* __restrict__ jout)               // (NB, NJ, 3)
{
    const int t = threadIdx.x;

    if (blockIdx.x >= 512) {
        // ---- prep A ----
        int tg = (blockIdx.x - 512) * 256 + t;   // 0 .. MPAD*KPAD/8-1
        int v   = tg / 72;                        // 72 octets of 8 per row
        int oct = tg - v * 72;
        int k0  = oct * 8;
        float x = 0.f, y = 0.f, z = 0.f;
        if (v < NV) {
            x = v_template[v*3+0]; y = v_template[v*3+1]; z = v_template[v*3+2];
        }
        f16x8 out;
        #pragma unroll
        for (int i = 0; i < 8; ++i) {
            int k  = k0 + i;
            int j  = k >> 2;
            int k4 = k & 3;
            float val = 0.f;
            if (v < NV && j < NJ) {
                float w = weights[(size_t)v*NJ + j];
                float vh = (k4 == 0) ? x : (k4 == 1) ? y : (k4 == 2) ? z : 1.0f;
                val = w * vh;
            }
            out[i] = (_Float16)val;
        }
        *(f16x8*)(Aout + (size_t)v*KPAD + k0) = out;
        return;
    }

    // ---- kinematics for batch b ----
    __shared__ float M0[NJ][12];
    __shared__ float M1[NJ][12];
    __shared__ int   a0[NJ];
    __shared__ int   a1[NJ];

    const int b = blockIdx.x;

    if (t < NJ) {
        const int j = t;
        float z = pose[b*(NJ*3) + 3*j + 0];
        float y = pose[b*(NJ*3) + 3*j + 1];
        float x = pose[b*(NJ*3) + 3*j + 2];
        float cx = cosf(x), sx = sinf(x);
        float cy = cosf(y), sy = sinf(y);
        float cz = cosf(z), sz = sinf(z);
        float r00 = cz*cy;
        float r01 = cz*sy*sx - sz*cx;
        float r02 = cz*sy*cx + sz*sx;
        float r10 = sz*cy;
        float r11 = sz*sy*sx + cz*cx;
        float r12 = sz*sy*cx - cz*sx;
        float r20 = -sy;
        float r21 = cy*sx;
        float r22 = cy*cx;
        float t0, t1, t2;
        int p = parent[j];
        if (j == 0) {
            t0 = t_pose[0]; t1 = t_pose[1]; t2 = t_pose[2];
        } else {
            float ox = t_pose[3*j+0] - t_pose[3*p+0];
            float oy = t_pose[3*j+1] - t_pose[3*p+1];
            float oz = t_pose[3*j+2] - t_pose[3*p+2];
            float s;
            if (j == 1) {
                s = cbl[b];
            } else {
                int blid = bone_mapper[j];
                if (blid >= 0) {
                    float bv = bone_lengths[b*NBONES + blid];
                    s = 2.0f / (1.0f + expf(-bv*0.2f));   // 2*sigmoid(x/5)
                } else {
                    s = 1.0f;
                }
            }
            t0 = ox*s; t1 = oy*s; t2 = oz*s;
        }
        M0[j][0]=r00; M0[j][1]=r01; M0[j][2]=r02;  M0[j][3]=t0;
        M0[j][4]=r10; M0[j][5]=r11; M0[j][6]=r12;  M0[j][7]=t1;
        M0[j][8]=r20; M0[j][9]=r21; M0[j][10]=r22; M0[j][11]=t2;
        a0[j] = (j == 0) ? -1 : p;
    }
    __syncthreads();

    float* src = &M0[0][0]; float* dst = &M1[0][0];
    int* as = a0; int* ad = a1;
    for (int r = 0; r < 8; ++r) {
        if (t < NJ) {
            int a = as[t];
            const float* Mi = src + t*12;
            float* Do = dst + t*12;
            if (a >= 0) {
                const float* Mp = src + a*12;
                #pragma unroll
                for (int m = 0; m < 3; ++m) {
                    float p0 = Mp[m*4+0], p1 = Mp[m*4+1], p2 = Mp[m*4+2], p3 = Mp[m*4+3];
                    Do[m*4+0] = p0*Mi[0] + p1*Mi[4] + p2*Mi[8];
                    Do[m*4+1] = p0*Mi[1] + p1*Mi[5] + p2*Mi[9];
                    Do[m*4+2] = p0*Mi[2] + p1*Mi[6] + p2*Mi[10];
                    Do[m*4+3] = p0*Mi[3] + p1*Mi[7] + p2*Mi[11] + p3;
                }
                ad[t] = as[a];
            } else {
                #pragma unroll
                for (int e = 0; e < 12; ++e) Do[e] = Mi[e];
                ad[t] = -1;
            }
        }
        __syncthreads();
        float* tf = src; src = dst; dst = tf;
        int* ti = as; as = ad; ad = ti;
    }

    if (t < NJ) {
        const int j = t;
        const float* G = src + j*12;
        float sb = scale[b];
        float tr0 = trans[b*3+0], tr1 = trans[b*3+1], tr2 = trans[b*3+2];
        float* jo = jout + ((size_t)b*NJ + j)*3;
        jo[0] = G[3]*sb  + tr0;
        jo[1] = G[7]*sb  + tr1;
        jo[2] = G[11]*sb + tr2;
        float jx = t_pose[3*j+0], jy = t_pose[3*j+1], jz = t_pose[3*j+2];
        // G_rel row c: [G[c*4+0], G[c*4+1], G[c*4+2], G[c*4+3] - dot(Grow, J)]
        #pragma unroll
        for (int c = 0; c < 3; ++c) {
            float g0 = G[c*4+0], g1 = G[c*4+1], g2 = G[c*4+2];
            float g3 = G[c*4+3] - (g0*jx + g1*jy + g2*jz);
            f16x4 o;
            o[0] = (_Float16)g0; o[1] = (_Float16)g1;
            o[2] = (_Float16)g2; o[3] = (_Float16)g3;
            *(f16x4*)(Bt + (size_t)(b*3 + c)*KPAD + j*4) = o;
        }
    } else if (t < NJ + 48) {
        // zero the K-pad region [560, 576) for this batch's 3 rows
        int idx = t - NJ;
        int c  = idx >> 4;
        int kk = idx & 15;
        Bt[(size_t)(b*3 + c)*KPAD + 560 + kk] = (_Float16)0.f;
    }
}

// ---------------- Kernel 2: f16 MFMA GEMM + fused epilogue -----------------
// C[v, b*3+c] = sum_k A[v,k] * Bt[b*3+c, k];  V = C*scale[b] + trans[b,c].
// Block 256 thr = 4 waves (2x2), tile 128x96, K-step 32, mfma 16x16x32_f16.
__global__ __launch_bounds__(256) void gemm_kernel(
    const _Float16* __restrict__ A,        // (MPAD, KPAD) row-major
    const _Float16* __restrict__ Bt,       // (NN, KPAD) row-major
    const float* __restrict__ scale,       // (NB)
    const float* __restrict__ trans,       // (NB, 3)
    float* __restrict__ vout)              // (NB, NV, 3)
{
    __shared__ unsigned char smem[25088];
    _Float16* sA = (_Float16*)smem;                 // [BM][LDK] = 128*56*2 = 14336 B
    _Float16* sB = sA + BM*LDK;                     // [BN][LDK] =  96*56*2 = 10752 B

    const int t    = threadIdx.x;
    const int lane = t & 63;
    const int wid  = t >> 6;
    const int wm   = wid & 1;        // wave m: 0..1 (64 rows each)
    const int wn   = wid >> 1;       // wave n: 0..1 (48 cols each)
    const int ln   = lane & 15;
    const int kq   = lane >> 4;      // k-octet 0..3

    const int n0 = blockIdx.x * BN;  // N block (x fastest: A-tile L2 reuse)
    const int m0 = blockIdx.y * BM;

    f32x4 acc[4][3];
    #pragma unroll
    for (int mi = 0; mi < 4; ++mi)
        #pragma unroll
        for (int ni = 0; ni < 3; ++ni)
            acc[mi][ni] = (f32x4){0.f, 0.f, 0.f, 0.f};

    const int ar = t >> 2, aq = t & 3;   // A chunk: row ar, octet aq

    for (int ks = 0; ks < KSTEPS; ++ks) {
        const int kbase = ks * BK;
        __syncthreads();
        // stage A: 128 rows x 32 k = 512 x 16B chunks; thread does t and t+256
        {
            f16x8 va = *(const f16x8*)(A + (size_t)(m0 + ar)*KPAD + kbase + aq*8);
            *(f16x8*)(sA + ar*LDK + aq*8) = va;
            f16x8 vb = *(const f16x8*)(A + (size_t)(m0 + ar + 64)*KPAD + kbase + aq*8);
            *(f16x8*)(sA + (ar + 64)*LDK + aq*8) = vb;
        }
        // stage B: 96 rows x 32 k = 384 x 16B chunks
        {
            f16x8 vb = *(const f16x8*)(Bt + (size_t)(n0 + ar)*KPAD + kbase + aq*8);
            *(f16x8*)(sB + ar*LDK + aq*8) = vb;
            if (t < 128) {
                f16x8 vc = *(const f16x8*)(Bt + (size_t)(n0 + ar + 64)*KPAD + kbase + aq*8);
                *(f16x8*)(sB + (ar + 64)*LDK + aq*8) = vc;
            }
        }
        __syncthreads();

        f16x8 af[4], bf[3];
        #pragma unroll
        for (int mi = 0; mi < 4; ++mi)
            af[mi] = *(const f16x8*)(sA + (wm*64 + mi*16 + ln)*LDK + kq*8);
        #pragma unroll
        for (int ni = 0; ni < 3; ++ni)
            bf[ni] = *(const f16x8*)(sB + (wn*48 + ni*16 + ln)*LDK + kq*8);

        #pragma unroll
        for (int mi = 0; mi < 4; ++mi)
            #pragma unroll
            for (int ni = 0; ni < 3; ++ni)
                acc[mi][ni] = __builtin_amdgcn_mfma_f32_16x16x32_f16(
                    af[mi], bf[ni], acc[mi][ni], 0, 0, 0);
    }

    // ---- epilogue: per-wave LDS transpose -> coalesced dword stores ----
    __syncthreads();   // all waves done reading sA/sB
    float* eT = (float*)smem + wid * 1568;      // 32 x 49 floats per wave

    #pragma unroll
    for (int phase = 0; phase < 2; ++phase) {
        #pragma unroll
        for (int mm = 0; mm < 2; ++mm) {
            int mi = phase*2 + mm;
            #pragma unroll
            for (int ni = 0; ni < 3; ++ni) {
                #pragma unroll
                for (int r = 0; r < 4; ++r) {
                    int m_loc = mm*16 + (lane>>4)*4 + r;
                    int n_loc = ni*16 + ln;
                    eT[m_loc*49 + n_loc] = acc[mi][ni][r];
                }
            }
        }
        // 32 v x 16 b x 3 c = 1536 floats per wave; 24 per lane, coalesced
        const int nw = n0 + wn*48;          // wave's first n (divisible by 3)
        const int bw = nw / 3;              // wave's first batch
        #pragma unroll
        for (int it = 0; it < 24; ++it) {
            int flat = it*64 + lane;        // b_loc*96 + v_loc*3 + c
            int b_loc = flat / 96;
            int f96   = flat - b_loc*96;
            int v_loc = f96 / 3;
            int c     = f96 - v_loc*3;
            int bg = bw + b_loc;
            int vg = m0 + wm*64 + phase*32 + v_loc;
            if (vg < NV) {
                float val = eT[v_loc*49 + b_loc*3 + c];
                vout[((size_t)bg*NV + vg)*3 + c] = val * scale[bg] + trans[bg*3 + c];
            }
        }
    }
}

extern "C" void kernel_launch(void* const* d_in, const int* in_sizes, int n_in,
                              void* d_out, int out_size, void* d_ws, size_t ws_size,
                              hipStream_t stream) {
    const float* pose         = (const float*)d_in[0];
    const float* bone_lengths = (const float*)d_in[1];
    const float* cbl          = (const float*)d_in[2];
    const float* trans        = (const float*)d_in[3];
    const float* scale        = (const float*)d_in[4];
    const float* v_template   = (const float*)d_in[5];
    const float* t_pose       = (const float*)d_in[6];
    const float* weights      = (const float*)d_in[7];
    const int*   parent       = (const int*)d_in[8];
    const int*   bone_mapper  = (const int*)d_in[9];

    float* vout = (float*)d_out;                         // (NB,NV,3)
    float* jout = vout + (size_t)NB*NV*3;                // (NB,NJ,3)

    _Float16* Aout = (_Float16*)d_ws;                    // MPAD*KPAD*2 = 15.19 MB
    _Float16* Bt   = Aout + (size_t)MPAD*KPAD;           // NN*KPAD*2  =  1.77 MB

    prep_kin_kernel<<<512 + PREPB, 256, 0, stream>>>(
        pose, bone_lengths, cbl, trans, scale, v_template, t_pose,
        parent, bone_mapper, weights, Aout, Bt, jout);

    dim3 grid(NN/BN, MPAD/BM);                           // 16 x 103
    gemm_kernel<<<grid, 256, 0, stream>>>(Aout, Bt, scale, trans, vout);
}